// Round 11
// baseline (247.038 us; speedup 1.0000x reference)
//
#include <hip/hip_runtime.h>
#include <hip/hip_bf16.h>
#include <stdint.h>

// N=4096, D=1024, H=512, C=21. All inputs f32; d_out f32:
//   [labels 4096][cls_prob 4096*21][bbox 4096*84]
// Factored GCN: A = diag(r) X X^T diag(r) - I  (r_i = 1/||x_i||)
//   => A@S = diag(r)*(X @ (S^T R X)^T) - S.
// R11: block-range fusion of independent kernels -> 12 dispatches (was 19):
//   D1 nf+adj | D2 prep+mp1 | D3 STgemm+mp2 | D4 T2Tgemm+mp3 | D5 red0+jump
//   D6 h1 | D7 ST2 | D8 T2T2 | D9 red0 | D10 h2 | D11 heads(unsplit) | D12 soft

typedef __attribute__((ext_vector_type(8))) short short8;
typedef __attribute__((ext_vector_type(4))) float floatx4;

#define BK 32
#define LSTR 40  // LDS row stride (shorts); b128 reads conflict-free

__device__ __forceinline__ unsigned short bfbits(float f) {
  union { float f; unsigned int i; } u; u.f = f;
  unsigned int r = u.i + 0x7fffu + ((u.i >> 16) & 1);  // RNE
  return (unsigned short)(r >> 16);
}

// ---------------- device GEMM 64x64 tile ----------------
// MODE 0: f32 partials part[z*MN + row*N + col]
// MODE 1: ST[row*4096+col] = bf16(v)
// MODE 2: h[row*512+col] = bf16(relu(rinorm[row]*v - ST[col*4096+row] + bias[col]))
template <int MODE>
__device__ __forceinline__ void dev_gemm(
    const __hip_bfloat16* __restrict__ P, const __hip_bfloat16* __restrict__ Q,
    int KC, int ld, int N, float* __restrict__ part,
    const float* __restrict__ rinorm, const __hip_bfloat16* __restrict__ ST,
    const float* __restrict__ bias, __hip_bfloat16* __restrict__ outb,
    int bx, int by, int bz, int gy) {
  __shared__ short As[2][64 * LSTR];
  __shared__ short Bs[2][64 * LSTR];
  const int tid = threadIdx.x;
  const int w = tid >> 6, lane = tid & 63;
  const size_t m0 = (size_t)by * 64, n0 = (size_t)bx * 64;

  const int srow = tid >> 2, skoff = (tid & 3) * 8;
  const short* gA = (const short*)P + (m0 + srow) * (size_t)ld + (size_t)bz * KC + skoff;
  const short* gB = (const short*)Q + (n0 + srow) * (size_t)ld + (size_t)bz * KC + skoff;
  const int soff = srow * LSTR + skoff;

  const int wm = (w >> 1) * 32, wn = (w & 1) * 32;
  const int lr = lane & 15, ko = (lane >> 4) * 8;

  floatx4 acc[2][2];
#pragma unroll
  for (int i = 0; i < 2; ++i)
#pragma unroll
    for (int j = 0; j < 2; ++j) acc[i][j] = (floatx4){0.f, 0.f, 0.f, 0.f};

  const int nIter = KC / BK;
  short8 ra = *(const short8*)gA;
  short8 rb = *(const short8*)gB;
  *(short8*)&As[0][soff] = ra;
  *(short8*)&Bs[0][soff] = rb;
  if (nIter > 1) {
    ra = *(const short8*)(gA + BK);
    rb = *(const short8*)(gB + BK);
  }
  __syncthreads();

  for (int it = 0; it < nIter; ++it) {
    const int cur = it & 1;
    short8 av[2], bv[2];
#pragma unroll
    for (int t = 0; t < 2; ++t) av[t] = *(const short8*)&As[cur][(wm + t * 16 + lr) * LSTR + ko];
#pragma unroll
    for (int t = 0; t < 2; ++t) bv[t] = *(const short8*)&Bs[cur][(wn + t * 16 + lr) * LSTR + ko];
    if (it + 1 < nIter) {
      *(short8*)&As[cur ^ 1][soff] = ra;
      *(short8*)&Bs[cur ^ 1][soff] = rb;
      if (it + 2 < nIter) {
        const int off = (it + 2) * BK;
        ra = *(const short8*)(gA + off);
        rb = *(const short8*)(gB + off);
      }
    }
#pragma unroll
    for (int i = 0; i < 2; ++i)
#pragma unroll
      for (int j = 0; j < 2; ++j)
        acc[i][j] = __builtin_amdgcn_mfma_f32_16x16x32_bf16(av[i], bv[j], acc[i][j], 0, 0, 0);
    __syncthreads();
  }

  const size_t MN = (size_t)(gy * 64) * (size_t)N;
  float* cp = part + (size_t)bz * MN;
  const int rb4 = (lane >> 4) * 4;
#pragma unroll
  for (int i = 0; i < 2; ++i)
#pragma unroll
    for (int j = 0; j < 2; ++j)
#pragma unroll
      for (int r = 0; r < 4; ++r) {
        int row = (int)m0 + wm + i * 16 + rb4 + r;
        int col = (int)n0 + wn + j * 16 + lr;
        float v = acc[i][j][r];
        if (MODE == 0) {
          cp[(size_t)row * N + col] = v;
        } else if (MODE == 1) {
          outb[(size_t)row * 4096 + col] = __float2bfloat16(v);
        } else {
          v = rinorm[row] * v - __bfloat162float(ST[(size_t)col * 4096 + row]) + bias[col];
          outb[(size_t)row * 512 + col] = __float2bfloat16(fmaxf(v, 0.f));
        }
      }
}

// ---------------- device helpers ----------------
__device__ __forceinline__ void dev_minprop(const unsigned long long* __restrict__ adj,
                                            int* __restrict__ labels, int node, int lane) {
  unsigned long long w = adj[(size_t)node * 64 + lane];
  int m = 0x7fffffff;
  while (w) {
    int b = __builtin_ctzll(w);
    w &= w - 1;
    m = min(m, labels[lane * 64 + b]);
  }
  for (int o = 32; o; o >>= 1) m = min(m, __shfl_down(m, o));
  if (lane == 0 && m < labels[node]) atomicMin(&labels[node], m);
}

__device__ __forceinline__ void dev_red0(const float* __restrict__ part,
                                         __hip_bfloat16* __restrict__ out, int n, int i) {
  float4 v = *(const float4*)(part + i);
  for (int s = 1; s < 8; ++s) {
    float4 q = *(const float4*)(part + (size_t)s * n + i);
    v.x += q.x; v.y += q.y; v.z += q.z; v.w += q.w;
  }
  out[i] = __float2bfloat16(v.x);
  out[i + 1] = __float2bfloat16(v.y);
  out[i + 2] = __float2bfloat16(v.z);
  out[i + 3] = __float2bfloat16(v.w);
}

// ---------------- D1: nf + adj ----------------
__global__ __launch_bounds__(256) void K_nf_adj(
    const float* __restrict__ X, __hip_bfloat16* __restrict__ Xb, float* __restrict__ rinorm,
    const float4* __restrict__ rois, unsigned long long* __restrict__ adj,
    int* __restrict__ labels) {
  int blk = blockIdx.x, tid = threadIdx.x;
  int lane = tid & 63;
  if (blk < 1024) {  // nf
    int wave = (blk * 256 + tid) >> 6;
    const float4* row = (const float4*)(X + (size_t)wave * 1024);
    uint2* orow = (uint2*)((short*)Xb + (size_t)wave * 1024);
    float s = 0.f;
#pragma unroll
    for (int it = 0; it < 4; ++it) {
      float4 p = row[lane + it * 64];
      s += p.x * p.x + p.y * p.y + p.z * p.z + p.w * p.w;
      uint2 q;
      q.x = (unsigned int)bfbits(p.x) | ((unsigned int)bfbits(p.y) << 16);
      q.y = (unsigned int)bfbits(p.z) | ((unsigned int)bfbits(p.w) << 16);
      orow[lane + it * 64] = q;
    }
    for (int o = 32; o; o >>= 1) s += __shfl_down(s, o);
    if (lane == 0) rinorm[wave] = 1.f / fmaxf(sqrtf(s), 1e-6f);
  } else {  // adj + fused hook0
    int node = ((blk - 1024) * 256 + tid) >> 6;
    float4 bi = rois[node];
    unsigned long long myword = 0;
    int mn = node;
    for (int w = 0; w < 64; ++w) {
      int j = w * 64 + lane;
      float4 bj = rois[j];
      float iw = fminf(bi.z, bj.z) - fmaxf(bi.x, bj.x) + 1.0f;
      float ih = fminf(bi.w, bj.w) - fmaxf(bi.y, bj.y) + 1.0f;
      bool ov = (iw > 0.f) && (ih > 0.f) && (j != node);
      unsigned long long msk = __ballot(ov);
      if (lane == w) myword = msk;
      if (msk) mn = min(mn, w * 64 + (int)__builtin_ctzll(msk));
    }
    adj[(size_t)node * 64 + lane] = myword;
    if (lane == 0) labels[node] = mn;
  }
}

// ---------------- D2: prep + minprop ----------------
__global__ __launch_bounds__(256) void K_prep_mp(
    const __hip_bfloat16* __restrict__ Xb, const float* __restrict__ rinorm,
    const float* __restrict__ Wg1, const float* __restrict__ Wg2,
    const float* __restrict__ Wb, const float* __restrict__ Wc,
    __hip_bfloat16* __restrict__ XRT, __hip_bfloat16* __restrict__ Wg1T,
    __hip_bfloat16* __restrict__ Wg2T, __hip_bfloat16* __restrict__ WcatT,
    const unsigned long long* __restrict__ adj, int* __restrict__ labels) {
  __shared__ float s[32][33];
  const int tid = threadIdx.x;
  const int tx = tid & 31, ty = tid >> 5;
  int blk = blockIdx.x;
  if (blk < 4096) {
    int c0 = (blk & 31) * 32, r0 = (blk >> 5) * 32;
#pragma unroll
    for (int k = 0; k < 4; ++k) {
      int r = r0 + ty + k * 8;
      s[ty + k * 8][tx] = __bfloat162float(Xb[(size_t)r * 1024 + c0 + tx]) * rinorm[r];
    }
    __syncthreads();
#pragma unroll
    for (int k = 0; k < 4; ++k)
      XRT[(size_t)(c0 + ty + k * 8) * 4096 + r0 + tx] = __float2bfloat16(s[tx][ty + k * 8]);
  } else if (blk < 4608) {
    int l = blk - 4096;
    int c0 = (l & 15) * 32, r0 = (l >> 4) * 32;
#pragma unroll
    for (int k = 0; k < 4; ++k)
      s[ty + k * 8][tx] = Wg1[(size_t)(r0 + ty + k * 8) * 512 + c0 + tx];
    __syncthreads();
#pragma unroll
    for (int k = 0; k < 4; ++k)
      Wg1T[(size_t)(c0 + ty + k * 8) * 1024 + r0 + tx] = __float2bfloat16(s[tx][ty + k * 8]);
  } else if (blk < 4864) {
    int l = blk - 4608;
    int c0 = (l & 15) * 32, r0 = (l >> 4) * 32;
#pragma unroll
    for (int k = 0; k < 4; ++k)
      s[ty + k * 8][tx] = Wg2[(size_t)(r0 + ty + k * 8) * 512 + c0 + tx];
    __syncthreads();
#pragma unroll
    for (int k = 0; k < 4; ++k)
      Wg2T[(size_t)(c0 + ty + k * 8) * 512 + r0 + tx] = __float2bfloat16(s[tx][ty + k * 8]);
  } else if (blk < 5120) {
    int idx = (blk - 4864) * 256 + tid;
    int r = idx >> 9, k = idx & 511;
    float v = 0.f;
    if (r < 84) v = Wb[(size_t)k * 84 + r];
    else if (r < 105) v = Wc[(size_t)k * 21 + (r - 84)];
    WcatT[idx] = __float2bfloat16(v);
  } else {  // minprop 1
    int node = ((blk - 5120) * 256 + tid) >> 6;
    dev_minprop(adj, labels, node, tid & 63);
  }
}

// ---------------- D3/D4: gemm + minprop ----------------
template <int MODE>
__global__ __launch_bounds__(256) void K_gemm_mp(
    const __hip_bfloat16* __restrict__ P, const __hip_bfloat16* __restrict__ Q,
    int KC, int ld, int N, float* __restrict__ part,
    const float* __restrict__ rinorm, const __hip_bfloat16* __restrict__ ST,
    const float* __restrict__ bias, __hip_bfloat16* __restrict__ outb,
    int gx, int gy, int gemmBlocks,
    const unsigned long long* __restrict__ adj, int* __restrict__ labels) {
  int blk = blockIdx.x;
  if (blk < gemmBlocks) {
    int bx = blk % gx, by = (blk / gx) % gy, bz = blk / (gx * gy);
    dev_gemm<MODE>(P, Q, KC, ld, N, part, rinorm, ST, bias, outb, bx, by, bz, gy);
  } else {
    int node = ((blk - gemmBlocks) * 256 + threadIdx.x) >> 6;
    dev_minprop(adj, labels, node, threadIdx.x & 63);
  }
}

// plain gemm
template <int MODE>
__global__ __launch_bounds__(256) void K_gemm(
    const __hip_bfloat16* __restrict__ P, const __hip_bfloat16* __restrict__ Q,
    int KC, int ld, int N, float* __restrict__ part,
    const float* __restrict__ rinorm, const __hip_bfloat16* __restrict__ ST,
    const float* __restrict__ bias, __hip_bfloat16* __restrict__ outb, int gx, int gy) {
  int blk = blockIdx.x;
  int bx = blk % gx, by = (blk / gx) % gy, bz = blk / (gx * gy);
  dev_gemm<MODE>(P, Q, KC, ld, N, part, rinorm, ST, bias, outb, bx, by, bz, gy);
}

// ---------------- D5: red0 + jump ----------------
__global__ __launch_bounds__(256) void K_red0_jump(
    const float* __restrict__ part, __hip_bfloat16* __restrict__ out, int n,
    int* __restrict__ labels, float* __restrict__ outL) {
  int blk = blockIdx.x, t = threadIdx.x;
  if (blk < 512) {
    dev_red0(part, out, n, (blk * 256 + t) * 4);
  } else {  // full pointer-doubling compress + f32 label write (256 threads)
    __shared__ int a[4096];
    __shared__ int b[4096];
    for (int i = t; i < 4096; i += 256) a[i] = labels[i];
    __syncthreads();
    int* src = a;
    int* dst = b;
    for (int it = 0; it < 12; ++it) {
      for (int i = t; i < 4096; i += 256) dst[i] = src[src[i]];
      __syncthreads();
      int* tp = src; src = dst; dst = tp;
    }
    for (int i = t; i < 4096; i += 256) outL[i] = (float)src[i];
  }
}

// plain red0 (D9)
__global__ __launch_bounds__(256) void K_red0(const float* __restrict__ part,
                                              __hip_bfloat16* __restrict__ out, int n) {
  dev_red0(part, out, n, (blockIdx.x * 256 + threadIdx.x) * 4);
}

// ---------------- D12: heads single-partial -> bbox + softmax ----------------
__global__ __launch_bounds__(256) void K_red2soft(
    const float* __restrict__ part, const float* __restrict__ bb, const float* __restrict__ bc,
    float* __restrict__ bbox, float* __restrict__ cls) {
  int row = (blockIdx.x * 256 + threadIdx.x) >> 6;
  int lane = threadIdx.x & 63;
  size_t b = (size_t)row * 128 + lane;
  float v0 = part[b];
  float v1 = part[b + 64];
  bbox[(size_t)row * 84 + lane] = v0 + bb[lane];
  if (lane < 20) bbox[(size_t)row * 84 + 64 + lane] = v1 + bb[64 + lane];
  float lsrc = (lane >= 20 && lane < 41) ? v1 + bc[lane - 20] : 0.f;
  float lj = __shfl(lsrc, 20 + lane);
  float x = (lane < 21) ? lj : -1e30f;
  float m = x;
  for (int o = 16; o; o >>= 1) m = fmaxf(m, __shfl_xor(m, o));
  float e = (lane < 21) ? expf(x - m) : 0.f;
  float s = e;
  for (int o = 16; o; o >>= 1) s += __shfl_xor(s, o);
  if (lane < 21) cls[(size_t)row * 21 + lane] = e / s;
}

// ---------------- launch ----------------
extern "C" void kernel_launch(void* const* d_in, const int* in_sizes, int n_in,
                              void* d_out, int out_size, void* d_ws, size_t ws_size,
                              hipStream_t stream) {
  const float* rois = (const float*)d_in[0];
  const float* X    = (const float*)d_in[1];
  const float* Wg1  = (const float*)d_in[2];
  const float* bg1  = (const float*)d_in[3];
  const float* Wg2  = (const float*)d_in[4];
  const float* bg2  = (const float*)d_in[5];
  const float* Wb   = (const float*)d_in[6];
  const float* bb   = (const float*)d_in[7];
  const float* Wc   = (const float*)d_in[8];
  const float* bc   = (const float*)d_in[9];

  float* out        = (float*)d_out;
  float* out_labels = out;
  float* out_cls    = out + 4096;
  float* out_bbox   = out + 4096 + 4096 * 21;

  char* p = (char*)d_ws;
  auto carve = [&](size_t bytes) { char* r = p; p += (bytes + 255) & ~(size_t)255; return r; };
  int* labels           = (int*)carve(4096ull * 4);
  float* rinorm         = (float*)carve(4096ull * 4);
  __hip_bfloat16* WcatT = (__hip_bfloat16*)carve(128ull * 512 * 2);
  __hip_bfloat16* Wg2T  = (__hip_bfloat16*)carve(512ull * 512 * 2);
  __hip_bfloat16* Wg1T  = (__hip_bfloat16*)carve(512ull * 1024 * 2);
  __hip_bfloat16* T2T   = (__hip_bfloat16*)carve(512ull * 1024 * 2);
  __hip_bfloat16* h     = (__hip_bfloat16*)carve(4096ull * 512 * 2);
  __hip_bfloat16* ST    = (__hip_bfloat16*)carve(512ull * 4096 * 2);
  __hip_bfloat16* Xb    = (__hip_bfloat16*)carve(4096ull * 1024 * 2);
  __hip_bfloat16* XRT   = (__hip_bfloat16*)carve(1024ull * 4096 * 2);
  unsigned long long* adj = (unsigned long long*)carve(4096ull * 64 * 8);
  float* part           = (float*)carve(16ull * 1024 * 1024);

  // D1: nf + adj(+hook0)
  K_nf_adj<<<2048, 256, 0, stream>>>(X, Xb, rinorm, (const float4*)rois, adj, labels);
  // D2: prep + minprop1
  K_prep_mp<<<6144, 256, 0, stream>>>(Xb, rinorm, Wg1, Wg2, Wb, Wc,
                                      XRT, Wg1T, Wg2T, WcatT, adj, labels);
  // D3: ST1 = NT(Wg1T, Xb)  [512x4096, K=1024]  + minprop2
  K_gemm_mp<1><<<512 + 1024, 256, 0, stream>>>(Wg1T, Xb, 1024, 1024, 4096, part,
                                               nullptr, nullptr, nullptr, ST,
                                               64, 8, 512, adj, labels);
  // D4: T2T1 = NT(ST, XRT) split-8 [512x1024, K=4096] + minprop3
  K_gemm_mp<0><<<1024 + 1024, 256, 0, stream>>>(ST, XRT, 512, 4096, 1024, part,
                                                nullptr, nullptr, nullptr, nullptr,
                                                16, 8, 1024, adj, labels);
  // D5: red0(T2T1) + jump->labels
  K_red0_jump<<<513, 256, 0, stream>>>(part, T2T, 512 * 1024, labels, out_labels);
  // D6: h1 = relu(r*NT(Xb,T2T1) - S1 + bg1)
  K_gemm<2><<<512, 256, 0, stream>>>(Xb, T2T, 1024, 1024, 512, part,
                                     rinorm, ST, bg1, h, 8, 64);
  // D7: ST2 = NT(Wg2T, h)  [512x4096, K=512]
  K_gemm<1><<<512, 256, 0, stream>>>(Wg2T, h, 512, 512, 4096, part,
                                     nullptr, nullptr, nullptr, ST, 64, 8);
  // D8: T2T2 = NT(ST, XRT) split-8
  K_gemm<0><<<1024, 256, 0, stream>>>(ST, XRT, 512, 4096, 1024, part,
                                      nullptr, nullptr, nullptr, nullptr, 16, 8);
  // D9: red0(T2T2)
  K_red0<<<512, 256, 0, stream>>>(part, T2T, 512 * 1024);
  // D10: h2
  K_gemm<2><<<512, 256, 0, stream>>>(Xb, T2T, 1024, 1024, 512, part,
                                     rinorm, ST, bg2, h, 8, 64);
  // D11: heads = NT(h, WcatT) [4096x128, K=512] unsplit
  K_gemm<0><<<128, 256, 0, stream>>>(h, WcatT, 512, 512, 128, part,
                                     nullptr, nullptr, nullptr, nullptr, 2, 64);
  // D12: bbox + softmax
  K_red2soft<<<1024, 256, 0, stream>>>(part, bb, bc, out_bbox, out_cls);
}

// Round 12
// 225.717 us; speedup vs baseline: 1.0945x; 1.0945x over previous
//
#include <hip/hip_runtime.h>
#include <hip/hip_bf16.h>
#include <stdint.h>

// N=4096, D=1024, H=512, C=21. All inputs f32; d_out f32:
//   [labels 4096][cls_prob 4096*21][bbox 4096*84]
// Factored GCN: A = diag(r) X X^T diag(r) - I  (r_i = 1/||x_i||)
//   => A@S = diag(r)*(X @ (S^T R X)^T) - S.
// R12: R10 chassis (best, 237us; R11 fusion regressed). Deltas: T2T split-K
//      8->4 (halve partial traffic), heads split 4->2, CC hooks 5->3.

typedef __attribute__((ext_vector_type(8))) short short8;
typedef __attribute__((ext_vector_type(4))) float floatx4;

#define BK 32
#define LSTR 40  // LDS row stride in shorts; b128 reads at this stride are conflict-free

__device__ __forceinline__ unsigned short bfbits(float f) {
  union { float f; unsigned int i; } u; u.f = f;
  unsigned int r = u.i + 0x7fffu + ((u.i >> 16) & 1);  // RNE
  return (unsigned short)(r >> 16);
}

// ---------------- GEMM 64x64 tile: acc = P[M,KC@z] @ Q[N,KC@z]^T ----------------
// 4 waves, wave tile 32x32 (acc 2x2). Ping-pong LDS, global prefetch 1 iter ahead.
// MODE 0: f32 partials part[z*MN + row*N + col]
// MODE 1: ST[row*4096+col] = bf16(v)                          (S-layer, M=512)
// MODE 2: h[row*512+col] = bf16(relu(rinorm[row]*v - ST[col*4096+row] + bias[col]))
template <int MODE>
__global__ __launch_bounds__(256) void gemm64(
    const __hip_bfloat16* __restrict__ P, const __hip_bfloat16* __restrict__ Q,
    int KC, int ld, int N, float* __restrict__ part,
    const float* __restrict__ rinorm, const __hip_bfloat16* __restrict__ ST,
    const float* __restrict__ bias, __hip_bfloat16* __restrict__ outb) {
  __shared__ short As[2][64 * LSTR];
  __shared__ short Bs[2][64 * LSTR];
  const int tid = threadIdx.x;
  const int w = tid >> 6, lane = tid & 63;
  const size_t m0 = (size_t)blockIdx.y * 64, n0 = (size_t)blockIdx.x * 64;
  const int z = blockIdx.z;

  // staging: 64 rows x 32 shorts; 4 threads/row, 8 shorts each
  const int srow = tid >> 2, skoff = (tid & 3) * 8;
  const short* gA = (const short*)P + (m0 + srow) * (size_t)ld + (size_t)z * KC + skoff;
  const short* gB = (const short*)Q + (n0 + srow) * (size_t)ld + (size_t)z * KC + skoff;
  const int soff = srow * LSTR + skoff;

  const int wm = (w >> 1) * 32, wn = (w & 1) * 32;  // wave tile 32x32
  const int lr = lane & 15, ko = (lane >> 4) * 8;

  floatx4 acc[2][2];
#pragma unroll
  for (int i = 0; i < 2; ++i)
#pragma unroll
    for (int j = 0; j < 2; ++j) acc[i][j] = (floatx4){0.f, 0.f, 0.f, 0.f};

  const int nIter = KC / BK;
  short8 ra = *(const short8*)gA;
  short8 rb = *(const short8*)gB;
  *(short8*)&As[0][soff] = ra;
  *(short8*)&Bs[0][soff] = rb;
  if (nIter > 1) {
    ra = *(const short8*)(gA + BK);
    rb = *(const short8*)(gB + BK);
  }
  __syncthreads();

  for (int it = 0; it < nIter; ++it) {
    const int cur = it & 1;
    short8 av[2], bv[2];
#pragma unroll
    for (int t = 0; t < 2; ++t) av[t] = *(const short8*)&As[cur][(wm + t * 16 + lr) * LSTR + ko];
#pragma unroll
    for (int t = 0; t < 2; ++t) bv[t] = *(const short8*)&Bs[cur][(wn + t * 16 + lr) * LSTR + ko];
    if (it + 1 < nIter) {
      *(short8*)&As[cur ^ 1][soff] = ra;
      *(short8*)&Bs[cur ^ 1][soff] = rb;
      if (it + 2 < nIter) {
        const int off = (it + 2) * BK;
        ra = *(const short8*)(gA + off);
        rb = *(const short8*)(gB + off);
      }
    }
#pragma unroll
    for (int i = 0; i < 2; ++i)
#pragma unroll
      for (int j = 0; j < 2; ++j)
        acc[i][j] = __builtin_amdgcn_mfma_f32_16x16x32_bf16(av[i], bv[j], acc[i][j], 0, 0, 0);
    __syncthreads();
  }

  const size_t MN = (size_t)(gridDim.y * 64) * (size_t)N;
  float* cp = part + (size_t)z * MN;
  const int rb4 = (lane >> 4) * 4;
#pragma unroll
  for (int i = 0; i < 2; ++i)
#pragma unroll
    for (int j = 0; j < 2; ++j)
#pragma unroll
      for (int r = 0; r < 4; ++r) {
        int row = (int)m0 + wm + i * 16 + rb4 + r;
        int col = (int)n0 + wn + j * 16 + lr;
        float v = acc[i][j][r];
        if (MODE == 0) {
          cp[(size_t)row * N + col] = v;
        } else if (MODE == 1) {
          outb[(size_t)row * 4096 + col] = __float2bfloat16(v);  // ST coalesced
        } else {
          v = rinorm[row] * v - __bfloat162float(ST[(size_t)col * 4096 + row]) + bias[col];
          outb[(size_t)row * 512 + col] = __float2bfloat16(fmaxf(v, 0.f));
        }
      }
}

// ---------------- reduces ----------------
// red0: out[i] = bf16(sum_{s<ns} part[s*n + i]); float4 lanes
__global__ void k_red0(const float* __restrict__ part, __hip_bfloat16* __restrict__ out,
                       int n, int ns) {
  int i = (blockIdx.x * 256 + threadIdx.x) * 4;
  if (i >= n) return;
  float4 v = *(const float4*)(part + i);
  for (int s = 1; s < ns; ++s) {
    float4 q = *(const float4*)(part + (size_t)s * n + i);
    v.x += q.x; v.y += q.y; v.z += q.z; v.w += q.w;
  }
  out[i] = __float2bfloat16(v.x);
  out[i + 1] = __float2bfloat16(v.y);
  out[i + 2] = __float2bfloat16(v.z);
  out[i + 3] = __float2bfloat16(v.w);
}

// heads partials [2][4096,128] -> bbox f32 (+bb) + softmax(cls logits +bc)
__global__ void k_red2soft(const float* __restrict__ part, const float* __restrict__ bb,
                           const float* __restrict__ bc, float* __restrict__ bbox,
                           float* __restrict__ cls) {
  const size_t MN = 4096ull * 128;
  int row = (blockIdx.x * 256 + threadIdx.x) >> 6;
  int lane = threadIdx.x & 63;
  size_t b = (size_t)row * 128 + lane;
  float v0 = part[b] + part[MN + b];
  float v1 = part[b + 64] + part[MN + b + 64];
  bbox[(size_t)row * 84 + lane] = v0 + bb[lane];
  if (lane < 20) bbox[(size_t)row * 84 + 64 + lane] = v1 + bb[64 + lane];
  float lsrc = (lane >= 20 && lane < 41) ? v1 + bc[lane - 20] : 0.f;
  float lj = __shfl(lsrc, 20 + lane);
  float x = (lane < 21) ? lj : -1e30f;
  float m = x;
  for (int o = 16; o; o >>= 1) m = fmaxf(m, __shfl_xor(m, o));
  float e = (lane < 21) ? expf(x - m) : 0.f;
  float s = e;
  for (int o = 16; o; o >>= 1) s += __shfl_xor(s, o);
  if (lane < 21) cls[(size_t)row * 21 + lane] = e / s;
}

// ---------------- prep ----------------
__global__ void k_nf(const float* __restrict__ X, __hip_bfloat16* __restrict__ Xb,
                     float* __restrict__ rinorm) {
  int wave = (blockIdx.x * 256 + threadIdx.x) >> 6;
  int lane = threadIdx.x & 63;
  const float4* row = (const float4*)(X + (size_t)wave * 1024);
  uint2* orow = (uint2*)((short*)Xb + (size_t)wave * 1024);
  float s = 0.f;
#pragma unroll
  for (int it = 0; it < 4; ++it) {
    float4 p = row[lane + it * 64];
    s += p.x * p.x + p.y * p.y + p.z * p.z + p.w * p.w;
    uint2 q;
    q.x = (unsigned int)bfbits(p.x) | ((unsigned int)bfbits(p.y) << 16);
    q.y = (unsigned int)bfbits(p.z) | ((unsigned int)bfbits(p.w) << 16);
    orow[lane + it * 64] = q;
  }
  for (int o = 32; o; o >>= 1) s += __shfl_down(s, o);
  if (lane == 0) rinorm[wave] = 1.f / fmaxf(sqrtf(s), 1e-6f);
}

// merged prep: [0,4096) XRT transpose (Xb*rinorm), [4096,4608) Wg1T,
//              [4608,4864) Wg2T, [4864,5120) WcatT
__global__ void k_prep(const __hip_bfloat16* __restrict__ Xb, const float* __restrict__ rinorm,
                       const float* __restrict__ Wg1, const float* __restrict__ Wg2,
                       const float* __restrict__ Wb, const float* __restrict__ Wc,
                       __hip_bfloat16* __restrict__ XRT, __hip_bfloat16* __restrict__ Wg1T,
                       __hip_bfloat16* __restrict__ Wg2T, __hip_bfloat16* __restrict__ WcatT) {
  __shared__ float s[32][33];
  const int tid = threadIdx.x;
  const int tx = tid & 31, ty = tid >> 5;  // (32,8)
  int blk = blockIdx.x;
  if (blk < 4096) {
    int c0 = (blk & 31) * 32, r0 = (blk >> 5) * 32;
#pragma unroll
    for (int k = 0; k < 4; ++k) {
      int r = r0 + ty + k * 8;
      s[ty + k * 8][tx] = __bfloat162float(Xb[(size_t)r * 1024 + c0 + tx]) * rinorm[r];
    }
    __syncthreads();
#pragma unroll
    for (int k = 0; k < 4; ++k)
      XRT[(size_t)(c0 + ty + k * 8) * 4096 + r0 + tx] = __float2bfloat16(s[tx][ty + k * 8]);
  } else if (blk < 4608) {
    int l = blk - 4096;
    int c0 = (l & 15) * 32, r0 = (l >> 4) * 32;
#pragma unroll
    for (int k = 0; k < 4; ++k)
      s[ty + k * 8][tx] = Wg1[(size_t)(r0 + ty + k * 8) * 512 + c0 + tx];
    __syncthreads();
#pragma unroll
    for (int k = 0; k < 4; ++k)
      Wg1T[(size_t)(c0 + ty + k * 8) * 1024 + r0 + tx] = __float2bfloat16(s[tx][ty + k * 8]);
  } else if (blk < 4864) {
    int l = blk - 4608;
    int c0 = (l & 15) * 32, r0 = (l >> 4) * 32;
#pragma unroll
    for (int k = 0; k < 4; ++k)
      s[ty + k * 8][tx] = Wg2[(size_t)(r0 + ty + k * 8) * 512 + c0 + tx];
    __syncthreads();
#pragma unroll
    for (int k = 0; k < 4; ++k)
      Wg2T[(size_t)(c0 + ty + k * 8) * 512 + r0 + tx] = __float2bfloat16(s[tx][ty + k * 8]);
  } else {
    int idx = (blk - 4864) * 256 + tid;
    int r = idx >> 9, k = idx & 511;
    float v = 0.f;
    if (r < 84) v = Wb[(size_t)k * 84 + r];
    else if (r < 105) v = Wc[(size_t)k * 21 + (r - 84)];
    WcatT[idx] = __float2bfloat16(v);
  }
}

// ---------------- connected components ----------------
__global__ void k_adj(const float4* __restrict__ rois, unsigned long long* __restrict__ adj,
                      int* __restrict__ labels) {
  int wave = (blockIdx.x * 256 + threadIdx.x) >> 6;
  int lane = threadIdx.x & 63;
  float4 bi = rois[wave];
  unsigned long long myword = 0;
  int mn = wave;
  for (int w = 0; w < 64; ++w) {
    int j = w * 64 + lane;
    float4 bj = rois[j];
    float iw = fminf(bi.z, bj.z) - fmaxf(bi.x, bj.x) + 1.0f;
    float ih = fminf(bi.w, bj.w) - fmaxf(bi.y, bj.y) + 1.0f;
    bool ov = (iw > 0.f) && (ih > 0.f) && (j != wave);
    unsigned long long msk = __ballot(ov);
    if (lane == w) myword = msk;
    if (msk) mn = min(mn, w * 64 + (int)__builtin_ctzll(msk));
  }
  adj[(size_t)wave * 64 + lane] = myword;
  if (lane == 0) labels[wave] = mn;
}

__global__ void k_minprop(const unsigned long long* __restrict__ adj, int* __restrict__ labels) {
  int wave = (blockIdx.x * 256 + threadIdx.x) >> 6;
  int lane = threadIdx.x & 63;
  unsigned long long w = adj[(size_t)wave * 64 + lane];
  int m = 0x7fffffff;
  while (w) {
    int b = __builtin_ctzll(w);
    w &= w - 1;
    m = min(m, labels[lane * 64 + b]);
  }
  for (int o = 32; o; o >>= 1) m = min(m, __shfl_down(m, o));
  if (lane == 0 && m < labels[wave]) atomicMin(&labels[wave], m);
}

__global__ void k_jump(int* __restrict__ labels, float* __restrict__ outL) {
  __shared__ int a[4096];
  __shared__ int b[4096];
  int t = threadIdx.x;
  for (int i = t; i < 4096; i += 1024) a[i] = labels[i];
  __syncthreads();
  int* src = a;
  int* dst = b;
  for (int it = 0; it < 12; ++it) {
    for (int i = t; i < 4096; i += 1024) dst[i] = src[src[i]];
    __syncthreads();
    int* tp = src; src = dst; dst = tp;
  }
  for (int i = t; i < 4096; i += 1024) outL[i] = (float)src[i];
}

// ---------------- launch ----------------
extern "C" void kernel_launch(void* const* d_in, const int* in_sizes, int n_in,
                              void* d_out, int out_size, void* d_ws, size_t ws_size,
                              hipStream_t stream) {
  const float* rois = (const float*)d_in[0];
  const float* X    = (const float*)d_in[1];
  const float* Wg1  = (const float*)d_in[2];
  const float* bg1  = (const float*)d_in[3];
  const float* Wg2  = (const float*)d_in[4];
  const float* bg2  = (const float*)d_in[5];
  const float* Wb   = (const float*)d_in[6];
  const float* bb   = (const float*)d_in[7];
  const float* Wc   = (const float*)d_in[8];
  const float* bc   = (const float*)d_in[9];

  float* out        = (float*)d_out;
  float* out_labels = out;
  float* out_cls    = out + 4096;
  float* out_bbox   = out + 4096 + 4096 * 21;

  char* p = (char*)d_ws;
  auto carve = [&](size_t bytes) { char* r = p; p += (bytes + 255) & ~(size_t)255; return r; };
  int* labels           = (int*)carve(4096ull * 4);
  float* rinorm         = (float*)carve(4096ull * 4);
  __hip_bfloat16* WcatT = (__hip_bfloat16*)carve(128ull * 512 * 2);
  __hip_bfloat16* Wg2T  = (__hip_bfloat16*)carve(512ull * 512 * 2);
  __hip_bfloat16* Wg1T  = (__hip_bfloat16*)carve(512ull * 1024 * 2);
  __hip_bfloat16* T2T   = (__hip_bfloat16*)carve(512ull * 1024 * 2);
  __hip_bfloat16* h     = (__hip_bfloat16*)carve(4096ull * 512 * 2);
  __hip_bfloat16* ST    = (__hip_bfloat16*)carve(512ull * 4096 * 2);
  __hip_bfloat16* Xb    = (__hip_bfloat16*)carve(4096ull * 1024 * 2);
  __hip_bfloat16* XRT   = (__hip_bfloat16*)carve(1024ull * 4096 * 2);
  unsigned long long* adj = (unsigned long long*)carve(4096ull * 64 * 8);
  float* part           = (float*)carve(16ull * 1024 * 1024);

  // prep
  k_nf<<<1024, 256, 0, stream>>>(X, Xb, rinorm);
  k_prep<<<5120, 256, 0, stream>>>(Xb, rinorm, Wg1, Wg2, Wb, Wc, XRT, Wg1T, Wg2T, WcatT);

  // CC: adj + fused hook0, 3 atomic hooks, final compress+write
  k_adj<<<1024, 256, 0, stream>>>((const float4*)rois, adj, labels);
  for (int r = 0; r < 3; ++r) k_minprop<<<1024, 256, 0, stream>>>(adj, labels);
  k_jump<<<1, 1024, 0, stream>>>(labels, out_labels);

  // ---- layer 1 ----
  gemm64<1><<<dim3(64, 8), 256, 0, stream>>>(Wg1T, Xb, 1024, 1024, 4096, part,
                                             nullptr, nullptr, nullptr, ST);
  gemm64<0><<<dim3(16, 8, 4), 256, 0, stream>>>(ST, XRT, 1024, 4096, 1024, part,
                                                nullptr, nullptr, nullptr, nullptr);
  k_red0<<<512, 256, 0, stream>>>(part, T2T, 512 * 1024, 4);
  gemm64<2><<<dim3(8, 64), 256, 0, stream>>>(Xb, T2T, 1024, 1024, 512, part,
                                             rinorm, ST, bg1, h);
  // ---- layer 2 ----
  gemm64<1><<<dim3(64, 8), 256, 0, stream>>>(Wg2T, h, 512, 512, 4096, part,
                                             nullptr, nullptr, nullptr, ST);
  gemm64<0><<<dim3(16, 8, 4), 256, 0, stream>>>(ST, XRT, 1024, 4096, 1024, part,
                                                nullptr, nullptr, nullptr, nullptr);
  k_red0<<<512, 256, 0, stream>>>(part, T2T, 512 * 1024, 4);
  gemm64<2><<<dim3(8, 64), 256, 0, stream>>>(Xb, T2T, 1024, 1024, 512, part,
                                             rinorm, ST, bg2, h);
  // ---- heads + fused softmax ----
  gemm64<0><<<dim3(2, 64, 2), 256, 0, stream>>>(h, WcatT, 256, 512, 128, part,
                                                nullptr, nullptr, nullptr, nullptr);
  k_red2soft<<<1024, 256, 0, stream>>>(part, bb, bc, out_bbox, out_cls);
}

// Round 13
// 221.657 us; speedup vs baseline: 1.1145x; 1.0183x over previous
//
#include <hip/hip_runtime.h>
#include <hip/hip_bf16.h>
#include <stdint.h>

// N=4096, D=1024, H=512, C=21. All inputs f32; d_out f32:
//   [labels 4096][cls_prob 4096*21][bbox 4096*84]
// Factored GCN: A = diag(r) X X^T diag(r) - I  (r_i = 1/||x_i||)
//   => A@S = diag(r)*(X @ (S^T R X)^T) - S.
// R13 (on R12 chassis, 225.7us): heads gemm MODE3 writes bbox + in-kernel
//   softmax (drops red2soft + 4MB part traffic); CC hooks 3->2; adj merged
//   into nf dispatch. 14 dispatches.

typedef __attribute__((ext_vector_type(8))) short short8;
typedef __attribute__((ext_vector_type(4))) float floatx4;

#define BK 32
#define LSTR 40  // LDS row stride in shorts; b128 reads at this stride are conflict-free

__device__ __forceinline__ unsigned short bfbits(float f) {
  union { float f; unsigned int i; } u; u.f = f;
  unsigned int r = u.i + 0x7fffu + ((u.i >> 16) & 1);  // RNE
  return (unsigned short)(r >> 16);
}

// ---------------- GEMM 64x64 tile: acc = P[M,KC@z] @ Q[N,KC@z]^T ----------------
// 4 waves, wave tile 32x32 (acc 2x2). Ping-pong LDS, global prefetch 1 iter ahead.
// MODE 0: f32 partials part[z*MN + row*N + col]
// MODE 1: ST[row*4096+col] = bf16(v)
// MODE 2: h[row*512+col] = bf16(relu(rinorm[row]*v - ST[col*4096+row] + bias[col]))
// MODE 3: heads: bx=0 -> bbox cols 0..63; bx=1 -> bbox 64..83 + softmax(cls 84..104)
template <int MODE>
__global__ __launch_bounds__(256) void gemm64(
    const __hip_bfloat16* __restrict__ P, const __hip_bfloat16* __restrict__ Q,
    int KC, int ld, int N, float* __restrict__ part,
    const float* __restrict__ rinorm, const __hip_bfloat16* __restrict__ ST,
    const float* __restrict__ bias, __hip_bfloat16* __restrict__ outb,
    float* __restrict__ outf, float* __restrict__ cls, const float* __restrict__ bias2) {
  __shared__ short As[2][64 * LSTR];
  __shared__ short Bs[2][64 * LSTR];
  const int tid = threadIdx.x;
  const int w = tid >> 6, lane = tid & 63;
  const size_t m0 = (size_t)blockIdx.y * 64, n0 = (size_t)blockIdx.x * 64;
  const int z = blockIdx.z;

  // staging: 64 rows x 32 shorts; 4 threads/row, 8 shorts each
  const int srow = tid >> 2, skoff = (tid & 3) * 8;
  const short* gA = (const short*)P + (m0 + srow) * (size_t)ld + (size_t)z * KC + skoff;
  const short* gB = (const short*)Q + (n0 + srow) * (size_t)ld + (size_t)z * KC + skoff;
  const int soff = srow * LSTR + skoff;

  const int wm = (w >> 1) * 32, wn = (w & 1) * 32;  // wave tile 32x32
  const int lr = lane & 15, ko = (lane >> 4) * 8;

  floatx4 acc[2][2];
#pragma unroll
  for (int i = 0; i < 2; ++i)
#pragma unroll
    for (int j = 0; j < 2; ++j) acc[i][j] = (floatx4){0.f, 0.f, 0.f, 0.f};

  const int nIter = KC / BK;
  short8 ra = *(const short8*)gA;
  short8 rb = *(const short8*)gB;
  *(short8*)&As[0][soff] = ra;
  *(short8*)&Bs[0][soff] = rb;
  if (nIter > 1) {
    ra = *(const short8*)(gA + BK);
    rb = *(const short8*)(gB + BK);
  }
  __syncthreads();

  for (int it = 0; it < nIter; ++it) {
    const int cur = it & 1;
    short8 av[2], bv[2];
#pragma unroll
    for (int t = 0; t < 2; ++t) av[t] = *(const short8*)&As[cur][(wm + t * 16 + lr) * LSTR + ko];
#pragma unroll
    for (int t = 0; t < 2; ++t) bv[t] = *(const short8*)&Bs[cur][(wn + t * 16 + lr) * LSTR + ko];
    if (it + 1 < nIter) {
      *(short8*)&As[cur ^ 1][soff] = ra;
      *(short8*)&Bs[cur ^ 1][soff] = rb;
      if (it + 2 < nIter) {
        const int off = (it + 2) * BK;
        ra = *(const short8*)(gA + off);
        rb = *(const short8*)(gB + off);
      }
    }
#pragma unroll
    for (int i = 0; i < 2; ++i)
#pragma unroll
      for (int j = 0; j < 2; ++j)
        acc[i][j] = __builtin_amdgcn_mfma_f32_16x16x32_bf16(av[i], bv[j], acc[i][j], 0, 0, 0);
    __syncthreads();
  }

  const size_t MN = (size_t)(gridDim.y * 64) * (size_t)N;
  float* cp = part + (size_t)z * MN;
  float* lg = (float*)&As[0][0];  // MODE 3: 64x22 f32 logit stage (LDS dead after loop)
  const int rb4 = (lane >> 4) * 4;
#pragma unroll
  for (int i = 0; i < 2; ++i)
#pragma unroll
    for (int j = 0; j < 2; ++j)
#pragma unroll
      for (int r = 0; r < 4; ++r) {
        int row = (int)m0 + wm + i * 16 + rb4 + r;
        int col = (int)n0 + wn + j * 16 + lr;
        float v = acc[i][j][r];
        if (MODE == 0) {
          cp[(size_t)row * N + col] = v;
        } else if (MODE == 1) {
          outb[(size_t)row * 4096 + col] = __float2bfloat16(v);  // ST coalesced
        } else if (MODE == 2) {
          v = rinorm[row] * v - __bfloat162float(ST[(size_t)col * 4096 + row]) + bias[col];
          outb[(size_t)row * 512 + col] = __float2bfloat16(fmaxf(v, 0.f));
        } else {
          if (blockIdx.x == 0) {
            outf[(size_t)row * 84 + col] = v + bias[col];  // bbox cols 0..63
          } else {
            int lrow = wm + i * 16 + rb4 + r;  // 0..63
            if (col < 84) outf[(size_t)row * 84 + col] = v + bias[col];  // 64..83
            else if (col < 105) lg[lrow * 22 + (col - 84)] = v + bias2[col - 84];
          }
        }
      }
  if (MODE == 3) {
    __syncthreads();
    if (blockIdx.x == 1 && tid < 64) {
      const float* Lr = &lg[tid * 22];
      float m = Lr[0];
#pragma unroll
      for (int k = 1; k < 21; ++k) m = fmaxf(m, Lr[k]);
      float s = 0.f;
      float e[21];
#pragma unroll
      for (int k = 0; k < 21; ++k) { e[k] = expf(Lr[k] - m); s += e[k]; }
      float inv = 1.f / s;
      float* dst = &cls[(m0 + tid) * 21];
#pragma unroll
      for (int k = 0; k < 21; ++k) dst[k] = e[k] * inv;
    }
  }
}

// ---------------- reduces ----------------
// red0: out[i] = bf16(sum_{s<ns} part[s*n + i]); float4 lanes
__global__ void k_red0(const float* __restrict__ part, __hip_bfloat16* __restrict__ out,
                       int n, int ns) {
  int i = (blockIdx.x * 256 + threadIdx.x) * 4;
  if (i >= n) return;
  float4 v = *(const float4*)(part + i);
  for (int s = 1; s < ns; ++s) {
    float4 q = *(const float4*)(part + (size_t)s * n + i);
    v.x += q.x; v.y += q.y; v.z += q.z; v.w += q.w;
  }
  out[i] = __float2bfloat16(v.x);
  out[i + 1] = __float2bfloat16(v.y);
  out[i + 2] = __float2bfloat16(v.z);
  out[i + 3] = __float2bfloat16(v.w);
}

// ---------------- D1: nf + adj(+hook0) merged ----------------
__global__ void k_nf_adj(const float* __restrict__ X, __hip_bfloat16* __restrict__ Xb,
                         float* __restrict__ rinorm, const float4* __restrict__ rois,
                         unsigned long long* __restrict__ adj, int* __restrict__ labels) {
  int blk = blockIdx.x, tid = threadIdx.x;
  int lane = tid & 63;
  if (blk < 1024) {  // nf: rinorm + bf16 convert
    int wave = (blk * 256 + tid) >> 6;
    const float4* row = (const float4*)(X + (size_t)wave * 1024);
    uint2* orow = (uint2*)((short*)Xb + (size_t)wave * 1024);
    float s = 0.f;
#pragma unroll
    for (int it = 0; it < 4; ++it) {
      float4 p = row[lane + it * 64];
      s += p.x * p.x + p.y * p.y + p.z * p.z + p.w * p.w;
      uint2 q;
      q.x = (unsigned int)bfbits(p.x) | ((unsigned int)bfbits(p.y) << 16);
      q.y = (unsigned int)bfbits(p.z) | ((unsigned int)bfbits(p.w) << 16);
      orow[lane + it * 64] = q;
    }
    for (int o = 32; o; o >>= 1) s += __shfl_down(s, o);
    if (lane == 0) rinorm[wave] = 1.f / fmaxf(sqrtf(s), 1e-6f);
  } else {  // adj build + fused hook0
    int node = ((blk - 1024) * 256 + tid) >> 6;
    float4 bi = rois[node];
    unsigned long long myword = 0;
    int mn = node;
    for (int w = 0; w < 64; ++w) {
      int j = w * 64 + lane;
      float4 bj = rois[j];
      float iw = fminf(bi.z, bj.z) - fmaxf(bi.x, bj.x) + 1.0f;
      float ih = fminf(bi.w, bj.w) - fmaxf(bi.y, bj.y) + 1.0f;
      bool ov = (iw > 0.f) && (ih > 0.f) && (j != node);
      unsigned long long msk = __ballot(ov);
      if (lane == w) myword = msk;
      if (msk) mn = min(mn, w * 64 + (int)__builtin_ctzll(msk));
    }
    adj[(size_t)node * 64 + lane] = myword;
    if (lane == 0) labels[node] = mn;
  }
}

// merged prep: [0,4096) XRT transpose (Xb*rinorm), [4096,4608) Wg1T,
//              [4608,4864) Wg2T, [4864,5120) WcatT
__global__ void k_prep(const __hip_bfloat16* __restrict__ Xb, const float* __restrict__ rinorm,
                       const float* __restrict__ Wg1, const float* __restrict__ Wg2,
                       const float* __restrict__ Wb, const float* __restrict__ Wc,
                       __hip_bfloat16* __restrict__ XRT, __hip_bfloat16* __restrict__ Wg1T,
                       __hip_bfloat16* __restrict__ Wg2T, __hip_bfloat16* __restrict__ WcatT) {
  __shared__ float s[32][33];
  const int tid = threadIdx.x;
  const int tx = tid & 31, ty = tid >> 5;  // (32,8)
  int blk = blockIdx.x;
  if (blk < 4096) {
    int c0 = (blk & 31) * 32, r0 = (blk >> 5) * 32;
#pragma unroll
    for (int k = 0; k < 4; ++k) {
      int r = r0 + ty + k * 8;
      s[ty + k * 8][tx] = __bfloat162float(Xb[(size_t)r * 1024 + c0 + tx]) * rinorm[r];
    }
    __syncthreads();
#pragma unroll
    for (int k = 0; k < 4; ++k)
      XRT[(size_t)(c0 + ty + k * 8) * 4096 + r0 + tx] = __float2bfloat16(s[tx][ty + k * 8]);
  } else if (blk < 4608) {
    int l = blk - 4096;
    int c0 = (l & 15) * 32, r0 = (l >> 4) * 32;
#pragma unroll
    for (int k = 0; k < 4; ++k)
      s[ty + k * 8][tx] = Wg1[(size_t)(r0 + ty + k * 8) * 512 + c0 + tx];
    __syncthreads();
#pragma unroll
    for (int k = 0; k < 4; ++k)
      Wg1T[(size_t)(c0 + ty + k * 8) * 1024 + r0 + tx] = __float2bfloat16(s[tx][ty + k * 8]);
  } else if (blk < 4864) {
    int l = blk - 4608;
    int c0 = (l & 15) * 32, r0 = (l >> 4) * 32;
#pragma unroll
    for (int k = 0; k < 4; ++k)
      s[ty + k * 8][tx] = Wg2[(size_t)(r0 + ty + k * 8) * 512 + c0 + tx];
    __syncthreads();
#pragma unroll
    for (int k = 0; k < 4; ++k)
      Wg2T[(size_t)(c0 + ty + k * 8) * 512 + r0 + tx] = __float2bfloat16(s[tx][ty + k * 8]);
  } else {
    int idx = (blk - 4864) * 256 + tid;
    int r = idx >> 9, k = idx & 511;
    float v = 0.f;
    if (r < 84) v = Wb[(size_t)k * 84 + r];
    else if (r < 105) v = Wc[(size_t)k * 21 + (r - 84)];
    WcatT[idx] = __float2bfloat16(v);
  }
}

// ---------------- connected components ----------------
__global__ void k_minprop(const unsigned long long* __restrict__ adj, int* __restrict__ labels) {
  int wave = (blockIdx.x * 256 + threadIdx.x) >> 6;
  int lane = threadIdx.x & 63;
  unsigned long long w = adj[(size_t)wave * 64 + lane];
  int m = 0x7fffffff;
  while (w) {
    int b = __builtin_ctzll(w);
    w &= w - 1;
    m = min(m, labels[lane * 64 + b]);
  }
  for (int o = 32; o; o >>= 1) m = min(m, __shfl_down(m, o));
  if (lane == 0 && m < labels[wave]) atomicMin(&labels[wave], m);
}

__global__ void k_jump(int* __restrict__ labels, float* __restrict__ outL) {
  __shared__ int a[4096];
  __shared__ int b[4096];
  int t = threadIdx.x;
  for (int i = t; i < 4096; i += 1024) a[i] = labels[i];
  __syncthreads();
  int* src = a;
  int* dst = b;
  for (int it = 0; it < 12; ++it) {  // 2^12 >= 4096
    for (int i = t; i < 4096; i += 1024) dst[i] = src[src[i]];
    __syncthreads();
    int* tp = src; src = dst; dst = tp;
  }
  for (int i = t; i < 4096; i += 1024) outL[i] = (float)src[i];
}

// ---------------- launch ----------------
extern "C" void kernel_launch(void* const* d_in, const int* in_sizes, int n_in,
                              void* d_out, int out_size, void* d_ws, size_t ws_size,
                              hipStream_t stream) {
  const float* rois = (const float*)d_in[0];
  const float* X    = (const float*)d_in[1];
  const float* Wg1  = (const float*)d_in[2];
  const float* bg1  = (const float*)d_in[3];
  const float* Wg2  = (const float*)d_in[4];
  const float* bg2  = (const float*)d_in[5];
  const float* Wb   = (const float*)d_in[6];
  const float* bb   = (const float*)d_in[7];
  const float* Wc   = (const float*)d_in[8];
  const float* bc   = (const float*)d_in[9];

  float* out        = (float*)d_out;
  float* out_labels = out;
  float* out_cls    = out + 4096;
  float* out_bbox   = out + 4096 + 4096 * 21;

  char* p = (char*)d_ws;
  auto carve = [&](size_t bytes) { char* r = p; p += (bytes + 255) & ~(size_t)255; return r; };
  int* labels           = (int*)carve(4096ull * 4);
  float* rinorm         = (float*)carve(4096ull * 4);
  __hip_bfloat16* WcatT = (__hip_bfloat16*)carve(128ull * 512 * 2);
  __hip_bfloat16* Wg2T  = (__hip_bfloat16*)carve(512ull * 512 * 2);
  __hip_bfloat16* Wg1T  = (__hip_bfloat16*)carve(512ull * 1024 * 2);
  __hip_bfloat16* T2T   = (__hip_bfloat16*)carve(512ull * 1024 * 2);
  __hip_bfloat16* h     = (__hip_bfloat16*)carve(4096ull * 512 * 2);
  __hip_bfloat16* ST    = (__hip_bfloat16*)carve(512ull * 4096 * 2);
  __hip_bfloat16* Xb    = (__hip_bfloat16*)carve(4096ull * 1024 * 2);
  __hip_bfloat16* XRT   = (__hip_bfloat16*)carve(1024ull * 4096 * 2);
  unsigned long long* adj = (unsigned long long*)carve(4096ull * 64 * 8);
  float* part           = (float*)carve(16ull * 1024 * 1024);

  // D1: nf + adj(+hook0)
  k_nf_adj<<<2048, 256, 0, stream>>>(X, Xb, rinorm, (const float4*)rois, adj, labels);
  // D2: prep (transposes + Wcat)
  k_prep<<<5120, 256, 0, stream>>>(Xb, rinorm, Wg1, Wg2, Wb, Wc, XRT, Wg1T, Wg2T, WcatT);
  // CC: 2 atomic hooks (reach 3 hops >= diameter 2 + margin), final compress
  for (int r = 0; r < 2; ++r) k_minprop<<<1024, 256, 0, stream>>>(adj, labels);
  k_jump<<<1, 1024, 0, stream>>>(labels, out_labels);

  // ---- layer 1 ----
  gemm64<1><<<dim3(64, 8), 256, 0, stream>>>(Wg1T, Xb, 1024, 1024, 4096, part,
                                             nullptr, nullptr, nullptr, ST,
                                             nullptr, nullptr, nullptr);
  gemm64<0><<<dim3(16, 8, 4), 256, 0, stream>>>(ST, XRT, 1024, 4096, 1024, part,
                                                nullptr, nullptr, nullptr, nullptr,
                                                nullptr, nullptr, nullptr);
  k_red0<<<512, 256, 0, stream>>>(part, T2T, 512 * 1024, 4);
  gemm64<2><<<dim3(8, 64), 256, 0, stream>>>(Xb, T2T, 1024, 1024, 512, part,
                                             rinorm, ST, bg1, h,
                                             nullptr, nullptr, nullptr);
  // ---- layer 2 ----
  gemm64<1><<<dim3(64, 8), 256, 0, stream>>>(Wg2T, h, 512, 512, 4096, part,
                                             nullptr, nullptr, nullptr, ST,
                                             nullptr, nullptr, nullptr);
  gemm64<0><<<dim3(16, 8, 4), 256, 0, stream>>>(ST, XRT, 1024, 4096, 1024, part,
                                                nullptr, nullptr, nullptr, nullptr,
                                                nullptr, nullptr, nullptr);
  k_red0<<<512, 256, 0, stream>>>(part, T2T, 512 * 1024, 4);
  gemm64<2><<<dim3(8, 64), 256, 0, stream>>>(Xb, T2T, 1024, 1024, 512, part,
                                             rinorm, ST, bg2, h,
                                             nullptr, nullptr, nullptr);
  // ---- heads: unsplit K=512, direct bbox + fused softmax ----
  gemm64<3><<<dim3(2, 64), 256, 0, stream>>>(h, WcatT, 512, 512, 128, part,
                                             nullptr, nullptr, bb, nullptr,
                                             out_bbox, out_cls, bc);
}

// Round 14
// 206.069 us; speedup vs baseline: 1.1988x; 1.0756x over previous
//
#include <hip/hip_runtime.h>
#include <hip/hip_bf16.h>
#include <stdint.h>

// N=4096, D=1024, H=512, C=21. All inputs f32; d_out f32:
//   [labels 4096][cls_prob 4096*21][bbox 4096*84]
// Factored GCN: A = diag(r) X X^T diag(r) - I  (r_i = 1/||x_i||)
//   => A@S = diag(r)*(X @ (S^T R X)^T) - S.
// R14 (on R13, 221.7us): BK 32->64 — halves K-loop barrier count; 8 MFMAs
//   per wave between barriers. LSTR 72 (2-way LDS aliasing = free). All else
//   identical to R13. 14 dispatches.

typedef __attribute__((ext_vector_type(8))) short short8;
typedef __attribute__((ext_vector_type(4))) float floatx4;

#define BK 64
#define LSTR 72  // LDS row stride in shorts; b128 reads at this stride <=2-way aliased

__device__ __forceinline__ unsigned short bfbits(float f) {
  union { float f; unsigned int i; } u; u.f = f;
  unsigned int r = u.i + 0x7fffu + ((u.i >> 16) & 1);  // RNE
  return (unsigned short)(r >> 16);
}

// ---------------- GEMM 64x64 tile: acc = P[M,KC@z] @ Q[N,KC@z]^T ----------------
// 4 waves, wave tile 32x32 (acc 2x2). Ping-pong LDS, global prefetch 1 iter ahead.
// MODE 0: f32 partials part[z*MN + row*N + col]
// MODE 1: ST[row*4096+col] = bf16(v)
// MODE 2: h[row*512+col] = bf16(relu(rinorm[row]*v - ST[col*4096+row] + bias[col]))
// MODE 3: heads: bx=0 -> bbox cols 0..63; bx=1 -> bbox 64..83 + softmax(cls 84..104)
template <int MODE>
__global__ __launch_bounds__(256) void gemm64(
    const __hip_bfloat16* __restrict__ P, const __hip_bfloat16* __restrict__ Q,
    int KC, int ld, int N, float* __restrict__ part,
    const float* __restrict__ rinorm, const __hip_bfloat16* __restrict__ ST,
    const float* __restrict__ bias, __hip_bfloat16* __restrict__ outb,
    float* __restrict__ outf, float* __restrict__ cls, const float* __restrict__ bias2) {
  __shared__ short As[2][64 * LSTR];
  __shared__ short Bs[2][64 * LSTR];
  const int tid = threadIdx.x;
  const int w = tid >> 6, lane = tid & 63;
  const size_t m0 = (size_t)blockIdx.y * 64, n0 = (size_t)blockIdx.x * 64;
  const int z = blockIdx.z;

  // staging: 64 rows x 64 shorts; 4 threads/row, 16 shorts (2x short8) each
  const int srow = tid >> 2, skoff = (tid & 3) * 16;
  const short* gA = (const short*)P + (m0 + srow) * (size_t)ld + (size_t)z * KC + skoff;
  const short* gB = (const short*)Q + (n0 + srow) * (size_t)ld + (size_t)z * KC + skoff;
  const int soff = srow * LSTR + skoff;

  const int wm = (w >> 1) * 32, wn = (w & 1) * 32;  // wave tile 32x32
  const int lr = lane & 15, ko = (lane >> 4) * 8;

  floatx4 acc[2][2];
#pragma unroll
  for (int i = 0; i < 2; ++i)
#pragma unroll
    for (int j = 0; j < 2; ++j) acc[i][j] = (floatx4){0.f, 0.f, 0.f, 0.f};

  const int nIter = KC / BK;
  short8 ra0 = *(const short8*)gA;
  short8 ra1 = *(const short8*)(gA + 8);
  short8 rb0 = *(const short8*)gB;
  short8 rb1 = *(const short8*)(gB + 8);
  *(short8*)&As[0][soff] = ra0;
  *(short8*)&As[0][soff + 8] = ra1;
  *(short8*)&Bs[0][soff] = rb0;
  *(short8*)&Bs[0][soff + 8] = rb1;
  if (nIter > 1) {
    ra0 = *(const short8*)(gA + BK);
    ra1 = *(const short8*)(gA + BK + 8);
    rb0 = *(const short8*)(gB + BK);
    rb1 = *(const short8*)(gB + BK + 8);
  }
  __syncthreads();

  for (int it = 0; it < nIter; ++it) {
    const int cur = it & 1;
    short8 av[2][2], bv[2][2];  // [k-step][tile]
#pragma unroll
    for (int ks = 0; ks < 2; ++ks)
#pragma unroll
      for (int t = 0; t < 2; ++t) {
        av[ks][t] = *(const short8*)&As[cur][(wm + t * 16 + lr) * LSTR + ks * 32 + ko];
        bv[ks][t] = *(const short8*)&Bs[cur][(wn + t * 16 + lr) * LSTR + ks * 32 + ko];
      }
    if (it + 1 < nIter) {
      *(short8*)&As[cur ^ 1][soff] = ra0;
      *(short8*)&As[cur ^ 1][soff + 8] = ra1;
      *(short8*)&Bs[cur ^ 1][soff] = rb0;
      *(short8*)&Bs[cur ^ 1][soff + 8] = rb1;
      if (it + 2 < nIter) {
        const int off = (it + 2) * BK;
        ra0 = *(const short8*)(gA + off);
        ra1 = *(const short8*)(gA + off + 8);
        rb0 = *(const short8*)(gB + off);
        rb1 = *(const short8*)(gB + off + 8);
      }
    }
#pragma unroll
    for (int ks = 0; ks < 2; ++ks)  // ascending K keeps accumulation order identical
#pragma unroll
      for (int i = 0; i < 2; ++i)
#pragma unroll
        for (int j = 0; j < 2; ++j)
          acc[i][j] = __builtin_amdgcn_mfma_f32_16x16x32_bf16(av[ks][i], bv[ks][j], acc[i][j], 0, 0, 0);
    __syncthreads();
  }

  const size_t MN = (size_t)(gridDim.y * 64) * (size_t)N;
  float* cp = part + (size_t)z * MN;
  float* lg = (float*)&As[0][0];  // MODE 3: 64x22 f32 logit stage (LDS dead after loop)
  const int rb4 = (lane >> 4) * 4;
#pragma unroll
  for (int i = 0; i < 2; ++i)
#pragma unroll
    for (int j = 0; j < 2; ++j)
#pragma unroll
      for (int r = 0; r < 4; ++r) {
        int row = (int)m0 + wm + i * 16 + rb4 + r;
        int col = (int)n0 + wn + j * 16 + lr;
        float v = acc[i][j][r];
        if (MODE == 0) {
          cp[(size_t)row * N + col] = v;
        } else if (MODE == 1) {
          outb[(size_t)row * 4096 + col] = __float2bfloat16(v);  // ST coalesced
        } else if (MODE == 2) {
          v = rinorm[row] * v - __bfloat162float(ST[(size_t)col * 4096 + row]) + bias[col];
          outb[(size_t)row * 512 + col] = __float2bfloat16(fmaxf(v, 0.f));
        } else {
          if (blockIdx.x == 0) {
            outf[(size_t)row * 84 + col] = v + bias[col];  // bbox cols 0..63
          } else {
            int lrow = wm + i * 16 + rb4 + r;  // 0..63
            if (col < 84) outf[(size_t)row * 84 + col] = v + bias[col];  // 64..83
            else if (col < 105) lg[lrow * 22 + (col - 84)] = v + bias2[col - 84];
          }
        }
      }
  if (MODE == 3) {
    __syncthreads();
    if (blockIdx.x == 1 && tid < 64) {
      const float* Lr = &lg[tid * 22];
      float m = Lr[0];
#pragma unroll
      for (int k = 1; k < 21; ++k) m = fmaxf(m, Lr[k]);
      float s = 0.f;
      float e[21];
#pragma unroll
      for (int k = 0; k < 21; ++k) { e[k] = expf(Lr[k] - m); s += e[k]; }
      float inv = 1.f / s;
      float* dst = &cls[(m0 + tid) * 21];
#pragma unroll
      for (int k = 0; k < 21; ++k) dst[k] = e[k] * inv;
    }
  }
}

// ---------------- reduces ----------------
// red0: out[i] = bf16(sum_{s<ns} part[s*n + i]); float4 lanes
__global__ void k_red0(const float* __restrict__ part, __hip_bfloat16* __restrict__ out,
                       int n, int ns) {
  int i = (blockIdx.x * 256 + threadIdx.x) * 4;
  if (i >= n) return;
  float4 v = *(const float4*)(part + i);
  for (int s = 1; s < ns; ++s) {
    float4 q = *(const float4*)(part + (size_t)s * n + i);
    v.x += q.x; v.y += q.y; v.z += q.z; v.w += q.w;
  }
  out[i] = __float2bfloat16(v.x);
  out[i + 1] = __float2bfloat16(v.y);
  out[i + 2] = __float2bfloat16(v.z);
  out[i + 3] = __float2bfloat16(v.w);
}

// ---------------- D1: nf + adj(+hook0) merged ----------------
__global__ void k_nf_adj(const float* __restrict__ X, __hip_bfloat16* __restrict__ Xb,
                         float* __restrict__ rinorm, const float4* __restrict__ rois,
                         unsigned long long* __restrict__ adj, int* __restrict__ labels) {
  int blk = blockIdx.x, tid = threadIdx.x;
  int lane = tid & 63;
  if (blk < 1024) {  // nf: rinorm + bf16 convert
    int wave = (blk * 256 + tid) >> 6;
    const float4* row = (const float4*)(X + (size_t)wave * 1024);
    uint2* orow = (uint2*)((short*)Xb + (size_t)wave * 1024);
    float s = 0.f;
#pragma unroll
    for (int it = 0; it < 4; ++it) {
      float4 p = row[lane + it * 64];
      s += p.x * p.x + p.y * p.y + p.z * p.z + p.w * p.w;
      uint2 q;
      q.x = (unsigned int)bfbits(p.x) | ((unsigned int)bfbits(p.y) << 16);
      q.y = (unsigned int)bfbits(p.z) | ((unsigned int)bfbits(p.w) << 16);
      orow[lane + it * 64] = q;
    }
    for (int o = 32; o; o >>= 1) s += __shfl_down(s, o);
    if (lane == 0) rinorm[wave] = 1.f / fmaxf(sqrtf(s), 1e-6f);
  } else {  // adj build + fused hook0
    int node = ((blk - 1024) * 256 + tid) >> 6;
    float4 bi = rois[node];
    unsigned long long myword = 0;
    int mn = node;
    for (int w = 0; w < 64; ++w) {
      int j = w * 64 + lane;
      float4 bj = rois[j];
      float iw = fminf(bi.z, bj.z) - fmaxf(bi.x, bj.x) + 1.0f;
      float ih = fminf(bi.w, bj.w) - fmaxf(bi.y, bj.y) + 1.0f;
      bool ov = (iw > 0.f) && (ih > 0.f) && (j != node);
      unsigned long long msk = __ballot(ov);
      if (lane == w) myword = msk;
      if (msk) mn = min(mn, w * 64 + (int)__builtin_ctzll(msk));
    }
    adj[(size_t)node * 64 + lane] = myword;
    if (lane == 0) labels[node] = mn;
  }
}

// merged prep: [0,4096) XRT transpose (Xb*rinorm), [4096,4608) Wg1T,
//              [4608,4864) Wg2T, [4864,5120) WcatT
__global__ void k_prep(const __hip_bfloat16* __restrict__ Xb, const float* __restrict__ rinorm,
                       const float* __restrict__ Wg1, const float* __restrict__ Wg2,
                       const float* __restrict__ Wb, const float* __restrict__ Wc,
                       __hip_bfloat16* __restrict__ XRT, __hip_bfloat16* __restrict__ Wg1T,
                       __hip_bfloat16* __restrict__ Wg2T, __hip_bfloat16* __restrict__ WcatT) {
  __shared__ float s[32][33];
  const int tid = threadIdx.x;
  const int tx = tid & 31, ty = tid >> 5;  // (32,8)
  int blk = blockIdx.x;
  if (blk < 4096) {
    int c0 = (blk & 31) * 32, r0 = (blk >> 5) * 32;
#pragma unroll
    for (int k = 0; k < 4; ++k) {
      int r = r0 + ty + k * 8;
      s[ty + k * 8][tx] = __bfloat162float(Xb[(size_t)r * 1024 + c0 + tx]) * rinorm[r];
    }
    __syncthreads();
#pragma unroll
    for (int k = 0; k < 4; ++k)
      XRT[(size_t)(c0 + ty + k * 8) * 4096 + r0 + tx] = __float2bfloat16(s[tx][ty + k * 8]);
  } else if (blk < 4608) {
    int l = blk - 4096;
    int c0 = (l & 15) * 32, r0 = (l >> 4) * 32;
#pragma unroll
    for (int k = 0; k < 4; ++k)
      s[ty + k * 8][tx] = Wg1[(size_t)(r0 + ty + k * 8) * 512 + c0 + tx];
    __syncthreads();
#pragma unroll
    for (int k = 0; k < 4; ++k)
      Wg1T[(size_t)(c0 + ty + k * 8) * 1024 + r0 + tx] = __float2bfloat16(s[tx][ty + k * 8]);
  } else if (blk < 4864) {
    int l = blk - 4608;
    int c0 = (l & 15) * 32, r0 = (l >> 4) * 32;
#pragma unroll
    for (int k = 0; k < 4; ++k)
      s[ty + k * 8][tx] = Wg2[(size_t)(r0 + ty + k * 8) * 512 + c0 + tx];
    __syncthreads();
#pragma unroll
    for (int k = 0; k < 4; ++k)
      Wg2T[(size_t)(c0 + ty + k * 8) * 512 + r0 + tx] = __float2bfloat16(s[tx][ty + k * 8]);
  } else {
    int idx = (blk - 4864) * 256 + tid;
    int r = idx >> 9, k = idx & 511;
    float v = 0.f;
    if (r < 84) v = Wb[(size_t)k * 84 + r];
    else if (r < 105) v = Wc[(size_t)k * 21 + (r - 84)];
    WcatT[idx] = __float2bfloat16(v);
  }
}

// ---------------- connected components ----------------
__global__ void k_minprop(const unsigned long long* __restrict__ adj, int* __restrict__ labels) {
  int wave = (blockIdx.x * 256 + threadIdx.x) >> 6;
  int lane = threadIdx.x & 63;
  unsigned long long w = adj[(size_t)wave * 64 + lane];
  int m = 0x7fffffff;
  while (w) {
    int b = __builtin_ctzll(w);
    w &= w - 1;
    m = min(m, labels[lane * 64 + b]);
  }
  for (int o = 32; o; o >>= 1) m = min(m, __shfl_down(m, o));
  if (lane == 0 && m < labels[wave]) atomicMin(&labels[wave], m);
}

__global__ void k_jump(int* __restrict__ labels, float* __restrict__ outL) {
  __shared__ int a[4096];
  __shared__ int b[4096];
  int t = threadIdx.x;
  for (int i = t; i < 4096; i += 1024) a[i] = labels[i];
  __syncthreads();
  int* src = a;
  int* dst = b;
  for (int it = 0; it < 12; ++it) {  // 2^12 >= 4096
    for (int i = t; i < 4096; i += 1024) dst[i] = src[src[i]];
    __syncthreads();
    int* tp = src; src = dst; dst = tp;
  }
  for (int i = t; i < 4096; i += 1024) outL[i] = (float)src[i];
}

// ---------------- launch ----------------
extern "C" void kernel_launch(void* const* d_in, const int* in_sizes, int n_in,
                              void* d_out, int out_size, void* d_ws, size_t ws_size,
                              hipStream_t stream) {
  const float* rois = (const float*)d_in[0];
  const float* X    = (const float*)d_in[1];
  const float* Wg1  = (const float*)d_in[2];
  const float* bg1  = (const float*)d_in[3];
  const float* Wg2  = (const float*)d_in[4];
  const float* bg2  = (const float*)d_in[5];
  const float* Wb   = (const float*)d_in[6];
  const float* bb   = (const float*)d_in[7];
  const float* Wc   = (const float*)d_in[8];
  const float* bc   = (const float*)d_in[9];

  float* out        = (float*)d_out;
  float* out_labels = out;
  float* out_cls    = out + 4096;
  float* out_bbox   = out + 4096 + 4096 * 21;

  char* p = (char*)d_ws;
  auto carve = [&](size_t bytes) { char* r = p; p += (bytes + 255) & ~(size_t)255; return r; };
  int* labels           = (int*)carve(4096ull * 4);
  float* rinorm         = (float*)carve(4096ull * 4);
  __hip_bfloat16* WcatT = (__hip_bfloat16*)carve(128ull * 512 * 2);
  __hip_bfloat16* Wg2T  = (__hip_bfloat16*)carve(512ull * 512 * 2);
  __hip_bfloat16* Wg1T  = (__hip_bfloat16*)carve(512ull * 1024 * 2);
  __hip_bfloat16* T2T   = (__hip_bfloat16*)carve(512ull * 1024 * 2);
  __hip_bfloat16* h     = (__hip_bfloat16*)carve(4096ull * 512 * 2);
  __hip_bfloat16* ST    = (__hip_bfloat16*)carve(512ull * 4096 * 2);
  __hip_bfloat16* Xb    = (__hip_bfloat16*)carve(4096ull * 1024 * 2);
  __hip_bfloat16* XRT   = (__hip_bfloat16*)carve(1024ull * 4096 * 2);
  unsigned long long* adj = (unsigned long long*)carve(4096ull * 64 * 8);
  float* part           = (float*)carve(16ull * 1024 * 1024);

  // D1: nf + adj(+hook0)
  k_nf_adj<<<2048, 256, 0, stream>>>(X, Xb, rinorm, (const float4*)rois, adj, labels);
  // D2: prep (transposes + Wcat)
  k_prep<<<5120, 256, 0, stream>>>(Xb, rinorm, Wg1, Wg2, Wb, Wc, XRT, Wg1T, Wg2T, WcatT);
  // CC: 2 atomic hooks, final compress
  for (int r = 0; r < 2; ++r) k_minprop<<<1024, 256, 0, stream>>>(adj, labels);
  k_jump<<<1, 1024, 0, stream>>>(labels, out_labels);

  // ---- layer 1 ----
  gemm64<1><<<dim3(64, 8), 256, 0, stream>>>(Wg1T, Xb, 1024, 1024, 4096, part,
                                             nullptr, nullptr, nullptr, ST,
                                             nullptr, nullptr, nullptr);
  gemm64<0><<<dim3(16, 8, 4), 256, 0, stream>>>(ST, XRT, 1024, 4096, 1024, part,
                                                nullptr, nullptr, nullptr, nullptr,
                                                nullptr, nullptr, nullptr);
  k_red0<<<512, 256, 0, stream>>>(part, T2T, 512 * 1024, 4);
  gemm64<2><<<dim3(8, 64), 256, 0, stream>>>(Xb, T2T, 1024, 1024, 512, part,
                                             rinorm, ST, bg1, h,
                                             nullptr, nullptr, nullptr);
  // ---- layer 2 ----
  gemm64<1><<<dim3(64, 8), 256, 0, stream>>>(Wg2T, h, 512, 512, 4096, part,
                                             nullptr, nullptr, nullptr, ST,
                                             nullptr, nullptr, nullptr);
  gemm64<0><<<dim3(16, 8, 4), 256, 0, stream>>>(ST, XRT, 1024, 4096, 1024, part,
                                                nullptr, nullptr, nullptr, nullptr,
                                                nullptr, nullptr, nullptr);
  k_red0<<<512, 256, 0, stream>>>(part, T2T, 512 * 1024, 4);
  gemm64<2><<<dim3(8, 64), 256, 0, stream>>>(Xb, T2T, 1024, 1024, 512, part,
                                             rinorm, ST, bg2, h,
                                             nullptr, nullptr, nullptr);
  // ---- heads: unsplit K=512, direct bbox + fused softmax ----
  gemm64<3><<<dim3(2, 64), 256, 0, stream>>>(h, WcatT, 512, 512, 128, part,
                                             nullptr, nullptr, bb, nullptr,
                                             out_bbox, out_cls, bc);
}